// Round 11
// baseline (228.901 us; speedup 1.0000x reference)
//
#include <hip/hip_runtime.h>
#include <hip/hip_bf16.h>
#include <stdint.h>

typedef int i32x4 __attribute__((ext_vector_type(4)));

// ---------------------------------------------------------------------------
// Pass 1: binarize f32 -> i8 sign (+1 / -1 / 0), both tensors in ONE dispatch
// (HBM-bound, ~45 us; unchanged)
// ---------------------------------------------------------------------------
__device__ __forceinline__ signed char sign_i8(float x) {
  return x > 0.0f ? (signed char)1 : (x < 0.0f ? (signed char)-1 : (signed char)0);
}

__global__ void binarize_i8_all(const float* __restrict__ x,
                                const float* __restrict__ w,
                                signed char* __restrict__ xb,
                                signed char* __restrict__ wb,
                                int n8x, int n8t) {
  int idx = blockIdx.x * blockDim.x + threadIdx.x;
  int stride = gridDim.x * blockDim.x;
  for (int i = idx; i < n8t; i += stride) {
    const float4* in4;
    uint2* out2;
    int j;
    if (i < n8x) { in4 = (const float4*)x; out2 = (uint2*)xb; j = i; }
    else         { in4 = (const float4*)w; out2 = (uint2*)wb; j = i - n8x; }
    float4 a = in4[2 * j];
    float4 b = in4[2 * j + 1];
    union { signed char c[8]; uint2 u; } p;
    p.c[0] = sign_i8(a.x); p.c[1] = sign_i8(a.y);
    p.c[2] = sign_i8(a.z); p.c[3] = sign_i8(a.w);
    p.c[4] = sign_i8(b.x); p.c[5] = sign_i8(b.y);
    p.c[6] = sign_i8(b.z); p.c[7] = sign_i8(b.w);
    out2[j] = p.u;
  }
}

// ---------------------------------------------------------------------------
// Pass 2: C = A * B^T, i8 +-1 inputs, i32 acc, f32 out (exact).
// Round 11: OCCUPANCY restructure. 128x128 block tile, 256 threads (4 waves,
// 1/SIMD), wave tile 64x64 (acc = 64 regs), mfma_i32_16x16x64_i8 with the
// proven zero-conflict XOR-swizzle geometry (rounds 5-9 measured 0
// conflicts). 3-buffer LDS rotation = 48 KiB -> 3 blocks/CU, 12 waves/CU:
// cross-block TLP covers barrier/stage stalls (previous rounds had ONE
// 8-wave block/CU -- every barrier idled the whole CU; all intra-wave
// pipelining grafts nulled, consistent with m131-m141/m114).
// __launch_bounds__(256,3): reg cap ~170, est need ~125 -> no spill
// (round 7 lesson: a too-tight cap spills acc -> GBs of scratch traffic).
// Flow schedule identical to proven round 8: counted waitvm<4>, ONE asm
// barrier per tile, stage(tt+2) issued after the barrier.
// Buffer safety (3-buf): stage(tt+2) rewrites buffer (tt+2)%3=(tt-1)%3,
// whose reads (iter tt-1) are lgkm-complete before iter tt-1's MFMAs, all
// before the top-of-tile-tt barrier; restage is issued after that barrier.
// ---------------------------------------------------------------------------
__device__ __forceinline__ void load_lds16(const void* g, void* l) {
  __builtin_amdgcn_global_load_lds(
      (const __attribute__((address_space(1))) void*)g,
      (__attribute__((address_space(3))) void*)l,
      16, 0, 0);
}

__device__ __forceinline__ void bar() {
  asm volatile("s_barrier" ::: "memory");
}
template <int N>
__device__ __forceinline__ void waitvm() {
  asm volatile("s_waitcnt vmcnt(%0)" ::"i"(N) : "memory");
}

__global__ __launch_bounds__(256, 3)
void gemm_bt_i8(const signed char* __restrict__ A,
                const signed char* __restrict__ B,
                float* __restrict__ C,
                int M, int N, int K, int nbn) {
  constexpr int BM = 128, BN = 128, BK = 64;
  // buffer = A tile (128x64 = 8KB) + B tile (8KB) = 16KB; 3 buffers = 48KB.
  __shared__ __attribute__((aligned(16))) char lds[3 * 16384];

  // XCD-aware bijective swizzle (grid = 64*32 = 2048, multiple of 8)
  int nwg = gridDim.x;
  int bid = blockIdx.x;
  int cpx = nwg >> 3;
  int swz = (bid & 7) * cpx + (bid >> 3);
  int tm = swz / nbn;
  int tn = swz % nbn;

  const int t = threadIdx.x;
  const int lane = t & 63;
  const int wid = t >> 6;       // 0..3
  const int wm = wid >> 1;      // 0..1  (wave row: 64 rows)
  const int wn = wid & 1;       // 0..1  (wave col: 64 cols)
  const int lrow = lane & 15;
  const int kg = lane >> 4;     // 0..3 (16 contiguous k-bytes each)

  const size_t rowA0 = (size_t)tm * BM;
  const size_t rowB0 = (size_t)tn * BN;

  i32x4 acc[4][4] = {};

  const int nt = K / BK;  // 64

  // --- staging lane constants (inverse-swizzled global source) ---
  // region = 8KB (A or B half of a buffer), 2 chunks of 4KB each; per chunk
  // a thread's byte off = c*4096 + wid*1024 + lane*16; row = off>>6 (64B
  // rows), physical 16B block = (off>>4)&3, logical = phys ^ ((row>>1)&3).
  const int off0 = wid * 1024 + lane * 16;
  const int srow0 = off0 >> 6;                       // 0..63
  const int scb0 = ((off0 >> 4) & 3) ^ ((srow0 >> 1) & 3);
  const int off1 = 4096 + wid * 1024 + lane * 16;
  const int srow1 = off1 >> 6;                       // 64..127
  const int scb1 = ((off1 >> 4) & 3) ^ ((srow1 >> 1) & 3);

  auto stage = [&](int tt) {
    const int b = tt % 3;
    const int k0 = tt * BK;
    char* L = lds + b * 16384;
    load_lds16(A + (rowA0 + srow0) * K + k0 + scb0 * 16, L + wid * 1024);
    load_lds16(A + (rowA0 + srow1) * K + k0 + scb1 * 16, L + 4096 + wid * 1024);
    load_lds16(B + (rowB0 + srow0) * K + k0 + scb0 * 16, L + 8192 + wid * 1024);
    load_lds16(B + (rowB0 + srow1) * K + k0 + scb1 * 16, L + 8192 + 4096 + wid * 1024);
  };

  // --- swizzled read column (byte) within a 64B LDS row (zero-conflict:
  // each ds_read_b128's 64 lanes cover 16 complete 64B rows) ---
  const int rcol = ((kg ^ ((lrow >> 1) & 3)) << 4);
  const int aoff = (wm * 64 + lrow) * 64 + rcol;
  const int boff = 8192 + (wn * 64 + lrow) * 64 + rcol;

  // prologue: stage tiles 0 and 1 (8 loads outstanding per thread)
  stage(0); stage(1);

  for (int tt = 0; tt < nt; ++tt) {
    const int b = tt % 3;
    // wait for tile tt's 4 loads (leave tile tt+1's 4 in flight)
    if (tt + 1 < nt) waitvm<4>(); else waitvm<0>();
    bar();  // the only barrier per tile

    const char* Ab = lds + b * 16384 + aoff;
    const char* Bb = lds + b * 16384 + boff;

    i32x4 af[4], bf[4];
    #pragma unroll
    for (int m = 0; m < 4; ++m)
      af[m] = *(const i32x4*)(Ab + m * 1024);
    #pragma unroll
    for (int n = 0; n < 4; ++n)
      bf[n] = *(const i32x4*)(Bb + n * 1024);

    if (tt + 2 < nt) stage(tt + 2);

    #pragma unroll
    for (int m = 0; m < 4; ++m)
      #pragma unroll
      for (int n = 0; n < 4; ++n)
        acc[m][n] = __builtin_amdgcn_mfma_i32_16x16x64_i8(af[m], bf[n], acc[m][n], 0, 0, 0);
  }

  // --- epilogue: C/D layout col = lane&15, row = (lane>>4)*4 + r ---
  // i32 -> f32 conversion is exact (|sum| <= 4096)
  const size_t cRow0 = rowA0 + (size_t)wm * 64;
  const size_t cCol0 = rowB0 + (size_t)wn * 64;
  const int orow = kg * 4;
  #pragma unroll
  for (int m = 0; m < 4; ++m)
    #pragma unroll
    for (int n = 0; n < 4; ++n)
      #pragma unroll
      for (int r = 0; r < 4; ++r)
        C[(cRow0 + m * 16 + orow + r) * N + cCol0 + n * 16 + lrow] =
            (float)acc[m][n][r];
}

// ---------------------------------------------------------------------------
extern "C" void kernel_launch(void* const* d_in, const int* in_sizes, int n_in,
                              void* d_out, int out_size, void* d_ws, size_t ws_size,
                              hipStream_t stream) {
  const float* x = (const float*)d_in[0];
  const float* w = (const float*)d_in[1];
  float* out = (float*)d_out;

  const int K = 4096;
  const int M = in_sizes[0] / K;   // 8192
  const int N = in_sizes[1] / K;   // 4096

  signed char* xb = (signed char*)d_ws;
  signed char* wb = xb + (size_t)M * K;

  int n8x = (M * K) / 8;
  int n8t = n8x + (N * K) / 8;
  binarize_i8_all<<<dim3(2048), dim3(256), 0, stream>>>(x, w, xb, wb, n8x, n8t);

  int nbm = M / 128;  // 64
  int nbn = N / 128;  // 32
  gemm_bt_i8<<<dim3(nbm * nbn), dim3(256), 0, stream>>>(
      xb, wb, out, M, N, K, nbn);
}

// Round 12
// 129.375 us; speedup vs baseline: 1.7693x; 1.7693x over previous
//
#include <hip/hip_runtime.h>
#include <hip/hip_bf16.h>
#include <stdint.h>

typedef int i32x4 __attribute__((ext_vector_type(4)));
typedef int i32x8 __attribute__((ext_vector_type(8)));
typedef float f32x4 __attribute__((ext_vector_type(4)));

// ---------------------------------------------------------------------------
// Pass 1: binarize f32 -> fp4 e2m1 sign nibble (+1=0x2, -1=0xA, 0=0x0),
// packed 2 elems/byte, low nibble = lower k index. 8 elems -> one u32.
// Both tensors in one dispatch (HBM-bound on the f32 reads).
// ---------------------------------------------------------------------------
__device__ __forceinline__ unsigned int sign_nib(float x) {
  return x > 0.0f ? 0x2u : (x < 0.0f ? 0xAu : 0x0u);
}

__global__ void binarize_fp4_all(const float* __restrict__ x,
                                 const float* __restrict__ w,
                                 unsigned int* __restrict__ xb,
                                 unsigned int* __restrict__ wb,
                                 int n8x, int n8t) {
  int idx = blockIdx.x * blockDim.x + threadIdx.x;
  int stride = gridDim.x * blockDim.x;
  for (int i = idx; i < n8t; i += stride) {
    const float4* in4;
    unsigned int* out32;
    int j;
    if (i < n8x) { in4 = (const float4*)x; out32 = xb; j = i; }
    else         { in4 = (const float4*)w; out32 = wb; j = i - n8x; }
    float4 a = in4[2 * j];
    float4 b = in4[2 * j + 1];
    unsigned int u = sign_nib(a.x)
                   | (sign_nib(a.y) << 4)
                   | (sign_nib(a.z) << 8)
                   | (sign_nib(a.w) << 12)
                   | (sign_nib(b.x) << 16)
                   | (sign_nib(b.y) << 20)
                   | (sign_nib(b.z) << 24)
                   | (sign_nib(b.w) << 28);
    out32[j] = u;
  }
}

// ---------------------------------------------------------------------------
// Pass 2: C = A * B^T, fp4 +-1/0 inputs, MX-scaled MFMA (scale=1.0), f32 out.
// EXACT: products are +-1/0, f32 accumulation of <=4096 integers is exact.
// 256x256 tile, BK=128 fp4 elems (= 64 B/row -> SAME byte geometry as the
// proven round-8 i8 kernel: 16 KB/matrix/tile staging, 64 B LDS rows,
// identical inverse-swizzled global_load_lds and zero-conflict XOR-swizzled
// 16 B fragment reads). 8 waves (2Mx4N), 4-buffer LDS rotation (128 KiB),
// counted vmcnt, ONE asm barrier per tile, stage(tt+2) after the barrier
// (buffer-rotation safety as in round 8). nt = 4096/128 = 32.
// mfma_scale_f32_16x16x128_f8f6f4, cbsz=blgp=4 (fp4), scale bytes 0x7F
// (E8M0 = 2^0). fp4 operands occupy the low 4 VGPRs of the v8i32 operand;
// upper 4 left undef via shufflevector. Fragments read in two half-phases
// (<=8 live v8i32) to keep unified regs ~232 < 256 (round-7 spill lesson).
// __launch_bounds__(512,2): do NOT request more waves/EU (acc spill).
// ---------------------------------------------------------------------------
__device__ __forceinline__ void load_lds16(const void* g, void* l) {
  __builtin_amdgcn_global_load_lds(
      (const __attribute__((address_space(1))) void*)g,
      (__attribute__((address_space(3))) void*)l,
      16, 0, 0);
}

__device__ __forceinline__ void bar() {
  asm volatile("s_barrier" ::: "memory");
}
template <int N>
__device__ __forceinline__ void waitvm() {
  asm volatile("s_waitcnt vmcnt(%0)" ::"i"(N) : "memory");
}

__device__ __forceinline__ i32x8 rd8(const char* p) {
  i32x4 q = *(const i32x4*)p;
  return __builtin_shufflevector(q, q, 0, 1, 2, 3, -1, -1, -1, -1);
}

__global__ __launch_bounds__(512, 2)
void gemm_bt_fp4(const unsigned char* __restrict__ A,
                 const unsigned char* __restrict__ B,
                 float* __restrict__ C,
                 int M, int N, int K, int nbn) {
  constexpr int BM = 256, BN = 256;
  __shared__ __attribute__((aligned(16))) char lds[4 * 32768];

  // XCD-aware bijective swizzle (grid = 32*16 = 512, multiple of 8)
  int nwg = gridDim.x;
  int bid = blockIdx.x;
  int cpx = nwg >> 3;
  int swz = (bid & 7) * cpx + (bid >> 3);
  int tm = swz / nbn;
  int tn = swz % nbn;

  const int t = threadIdx.x;
  const int lane = t & 63;
  const int wid = t >> 6;       // 0..7
  const int wm = wid >> 2;      // 0..1  (wave row: 128 rows)
  const int wn = wid & 3;       // 0..3  (wave col: 64 cols)
  const int lrow = lane & 15;
  const int kg = lane >> 4;     // 0..3 (32 contiguous fp4 k-elems = 16 B)

  const int Kb = K >> 1;        // row stride in bytes (fp4 packed)
  const size_t rowA0 = (size_t)tm * BM;
  const size_t rowB0 = (size_t)tn * BN;

  f32x4 acc[8][4] = {};

  const int nt = K / 128;  // 32

  // --- staging lane constants (inverse-swizzled global source; byte-
  // identical to round 8: 16KB region, 64B rows, blk = phys ^ ((row>>1)&3))
  const int soff0 = wid * 1024 + lane * 16;
  const int srow0 = soff0 >> 6;
  const int scb0 = ((soff0 >> 4) & 3) ^ ((srow0 >> 1) & 3);
  const int soff1 = 8192 + wid * 1024 + lane * 16;
  const int srow1 = soff1 >> 6;
  const int scb1 = ((soff1 >> 4) & 3) ^ ((srow1 >> 1) & 3);

  auto stage = [&](int tt) {
    const int b = tt & 3;
    const int k0b = tt * 64;    // tile K-offset in BYTES (128 fp4 = 64 B)
    load_lds16(A + (rowA0 + srow0) * Kb + k0b + scb0 * 16,
               lds + b * 32768 + wid * 1024);
    load_lds16(A + (rowA0 + srow1) * Kb + k0b + scb1 * 16,
               lds + b * 32768 + 8192 + wid * 1024);
    load_lds16(B + (rowB0 + srow0) * Kb + k0b + scb0 * 16,
               lds + b * 32768 + 16384 + wid * 1024);
    load_lds16(B + (rowB0 + srow1) * Kb + k0b + scb1 * 16,
               lds + b * 32768 + 16384 + 8192 + wid * 1024);
  };

  // --- swizzled read column (byte) within a 64B LDS row (proven 0-conflict)
  const int rcol = ((kg ^ ((lrow >> 1) & 3)) << 4);
  const int aoff = (wm * 128 + lrow) * 64 + rcol;
  const int boff = 16384 + (wn * 64 + lrow) * 64 + rcol;

  const int SC = 0x7F7F7F7F;  // E8M0 scale bytes: 127 -> 2^0

  // prologue: stage tiles 0 and 1 (8 loads outstanding per thread)
  stage(0); stage(1);

  for (int tt = 0; tt < nt; ++tt) {
    const int b = tt & 3;
    if (tt + 1 < nt) waitvm<4>(); else waitvm<0>();
    bar();  // the only barrier per tile

    const char* Ab = lds + b * 32768 + aoff;
    const char* Bb = lds + b * 32768 + boff;

    // half-phase 1: B frags + A frags 0..3, restage, 16 MFMAs
    i32x8 bf[4], af[4];
    #pragma unroll
    for (int n = 0; n < 4; ++n)
      bf[n] = rd8(Bb + n * 1024);
    #pragma unroll
    for (int m = 0; m < 4; ++m)
      af[m] = rd8(Ab + m * 1024);

    if (tt + 2 < nt) stage(tt + 2);

    #pragma unroll
    for (int m = 0; m < 4; ++m)
      #pragma unroll
      for (int n = 0; n < 4; ++n)
        acc[m][n] = __builtin_amdgcn_mfma_scale_f32_16x16x128_f8f6f4(
            af[m], bf[n], acc[m][n], 4, 4, 0, SC, 0, SC);

    // half-phase 2: A frags 4..7, 16 MFMAs
    i32x8 ag[4];
    #pragma unroll
    for (int m = 0; m < 4; ++m)
      ag[m] = rd8(Ab + (m + 4) * 1024);

    #pragma unroll
    for (int m = 0; m < 4; ++m)
      #pragma unroll
      for (int n = 0; n < 4; ++n)
        acc[m + 4][n] = __builtin_amdgcn_mfma_scale_f32_16x16x128_f8f6f4(
            ag[m], bf[n], acc[m + 4][n], 4, 4, 0, SC, 0, SC);
  }

  // --- epilogue: 16x16 C/D layout col = lane&15, row = (lane>>4)*4 + r ---
  const size_t cRow0 = rowA0 + (size_t)wm * 128;
  const size_t cCol0 = rowB0 + (size_t)wn * 64;
  const int orow = kg * 4;
  #pragma unroll
  for (int m = 0; m < 8; ++m)
    #pragma unroll
    for (int n = 0; n < 4; ++n)
      #pragma unroll
      for (int r = 0; r < 4; ++r)
        C[(cRow0 + m * 16 + orow + r) * N + cCol0 + n * 16 + lrow] =
            acc[m][n][r];
}

// ---------------------------------------------------------------------------
extern "C" void kernel_launch(void* const* d_in, const int* in_sizes, int n_in,
                              void* d_out, int out_size, void* d_ws, size_t ws_size,
                              hipStream_t stream) {
  const float* x = (const float*)d_in[0];
  const float* w = (const float*)d_in[1];
  float* out = (float*)d_out;

  const int K = 4096;
  const int M = in_sizes[0] / K;   // 8192
  const int N = in_sizes[1] / K;   // 4096

  unsigned char* xb = (unsigned char*)d_ws;
  unsigned char* wb = xb + (size_t)M * (K / 2);

  int n8x = (M * K) / 8;
  int n8t = n8x + (N * K) / 8;
  binarize_fp4_all<<<dim3(2048), dim3(256), 0, stream>>>(
      x, w, (unsigned int*)xb, (unsigned int*)wb, n8x, n8t);

  int nbm = M / 256;  // 32
  int nbn = N / 256;  // 16
  gemm_bt_fp4<<<dim3(nbm * nbn), dim3(512), 0, stream>>>(
      xb, wb, out, M, N, K, nbn);
}

// Round 13
// 121.513 us; speedup vs baseline: 1.8838x; 1.0647x over previous
//
#include <hip/hip_runtime.h>
#include <hip/hip_bf16.h>
#include <stdint.h>

typedef int i32x4 __attribute__((ext_vector_type(4)));
typedef int i32x8 __attribute__((ext_vector_type(8)));
typedef float f32x4 __attribute__((ext_vector_type(4)));

// ---------------------------------------------------------------------------
// Pass 1: binarize f32 -> fp4 e2m1 sign nibble (+1=0x2, -1=0xA, 0=0x0),
// packed 2 elems/byte, low nibble = lower k index.
// Round 13: single-pass, 32 floats/thread, 8 INDEPENDENT float4 loads issued
// back-to-back (max MLP -- the old grid-stride loop ran 12 serial dependent
// iterations and sat at 1.2 TB/s effective). Block-uniform x/w split (x is
// exactly 4096 of 6144 blocks), one uint4 store per thread.
// ---------------------------------------------------------------------------
__device__ __forceinline__ unsigned int sign_nib(float x) {
  return x > 0.0f ? 0x2u : (x < 0.0f ? 0xAu : 0x0u);
}

__device__ __forceinline__ unsigned int pack8(const float4& a, const float4& b) {
  return sign_nib(a.x)
       | (sign_nib(a.y) << 4)
       | (sign_nib(a.z) << 8)
       | (sign_nib(a.w) << 12)
       | (sign_nib(b.x) << 16)
       | (sign_nib(b.y) << 20)
       | (sign_nib(b.z) << 24)
       | (sign_nib(b.w) << 28);
}

__global__ __launch_bounds__(256)
void binarize_fp4_v2(const float* __restrict__ x,
                     const float* __restrict__ w,
                     uint4* __restrict__ xb,
                     uint4* __restrict__ wb,
                     int gx) {   // gx = number of 32-float groups in x
  int g = blockIdx.x * blockDim.x + threadIdx.x;
  const float4* src;
  uint4* dst;
  int j;
  if (g < gx) { src = (const float4*)x; dst = xb; j = g; }
  else        { src = (const float4*)w; dst = wb; j = g - gx; }

  const float4* p = src + (size_t)j * 8;
  // 8 independent loads -- issued before any packing (MLP)
  float4 v0 = p[0], v1 = p[1], v2 = p[2], v3 = p[3];
  float4 v4 = p[4], v5 = p[5], v6 = p[6], v7 = p[7];

  uint4 o;
  o.x = pack8(v0, v1);
  o.y = pack8(v2, v3);
  o.z = pack8(v4, v5);
  o.w = pack8(v6, v7);
  dst[j] = o;
}

// ---------------------------------------------------------------------------
// Pass 2: C = A * B^T, fp4 +-1/0 inputs, MX-scaled MFMA (scale=1.0), f32 out.
// EXACT: products are +-1/0, f32 accumulation of <=4096 integers is exact.
// UNCHANGED from round 12 (measured ~42 us ~= 93% of the fp4 16x16 MFMA
// ubench ceiling 7228 TF; conflicts 0). 256x256 tile, BK=128 fp4 (64 B/row,
// same byte geometry as the proven round-8 structure), 8 waves (2Mx4N),
// 4-buffer LDS rotation, counted vmcnt, ONE asm barrier per tile,
// stage(tt+2) after the barrier. nt = 32.
// ---------------------------------------------------------------------------
__device__ __forceinline__ void load_lds16(const void* g, void* l) {
  __builtin_amdgcn_global_load_lds(
      (const __attribute__((address_space(1))) void*)g,
      (__attribute__((address_space(3))) void*)l,
      16, 0, 0);
}

__device__ __forceinline__ void bar() {
  asm volatile("s_barrier" ::: "memory");
}
template <int N>
__device__ __forceinline__ void waitvm() {
  asm volatile("s_waitcnt vmcnt(%0)" ::"i"(N) : "memory");
}

__device__ __forceinline__ i32x8 rd8(const char* p) {
  i32x4 q = *(const i32x4*)p;
  return __builtin_shufflevector(q, q, 0, 1, 2, 3, -1, -1, -1, -1);
}

__global__ __launch_bounds__(512, 2)
void gemm_bt_fp4(const unsigned char* __restrict__ A,
                 const unsigned char* __restrict__ B,
                 float* __restrict__ C,
                 int M, int N, int K, int nbn) {
  constexpr int BM = 256, BN = 256;
  __shared__ __attribute__((aligned(16))) char lds[4 * 32768];

  // XCD-aware bijective swizzle (grid = 32*16 = 512, multiple of 8)
  int nwg = gridDim.x;
  int bid = blockIdx.x;
  int cpx = nwg >> 3;
  int swz = (bid & 7) * cpx + (bid >> 3);
  int tm = swz / nbn;
  int tn = swz % nbn;

  const int t = threadIdx.x;
  const int lane = t & 63;
  const int wid = t >> 6;       // 0..7
  const int wm = wid >> 2;      // 0..1  (wave row: 128 rows)
  const int wn = wid & 3;       // 0..3  (wave col: 64 cols)
  const int lrow = lane & 15;
  const int kg = lane >> 4;     // 0..3 (32 contiguous fp4 k-elems = 16 B)

  const int Kb = K >> 1;        // row stride in bytes (fp4 packed)
  const size_t rowA0 = (size_t)tm * BM;
  const size_t rowB0 = (size_t)tn * BN;

  f32x4 acc[8][4] = {};

  const int nt = K / 128;  // 32

  // --- staging lane constants (inverse-swizzled global source) ---
  const int soff0 = wid * 1024 + lane * 16;
  const int srow0 = soff0 >> 6;
  const int scb0 = ((soff0 >> 4) & 3) ^ ((srow0 >> 1) & 3);
  const int soff1 = 8192 + wid * 1024 + lane * 16;
  const int srow1 = soff1 >> 6;
  const int scb1 = ((soff1 >> 4) & 3) ^ ((srow1 >> 1) & 3);

  auto stage = [&](int tt) {
    const int b = tt & 3;
    const int k0b = tt * 64;    // tile K-offset in BYTES (128 fp4 = 64 B)
    load_lds16(A + (rowA0 + srow0) * Kb + k0b + scb0 * 16,
               lds + b * 32768 + wid * 1024);
    load_lds16(A + (rowA0 + srow1) * Kb + k0b + scb1 * 16,
               lds + b * 32768 + 8192 + wid * 1024);
    load_lds16(B + (rowB0 + srow0) * Kb + k0b + scb0 * 16,
               lds + b * 32768 + 16384 + wid * 1024);
    load_lds16(B + (rowB0 + srow1) * Kb + k0b + scb1 * 16,
               lds + b * 32768 + 16384 + 8192 + wid * 1024);
  };

  // --- swizzled read column (byte) within a 64B LDS row (proven 0-conflict)
  const int rcol = ((kg ^ ((lrow >> 1) & 3)) << 4);
  const int aoff = (wm * 128 + lrow) * 64 + rcol;
  const int boff = 16384 + (wn * 64 + lrow) * 64 + rcol;

  const int SC = 0x7F7F7F7F;  // E8M0 scale bytes: 127 -> 2^0

  // prologue: stage tiles 0 and 1 (8 loads outstanding per thread)
  stage(0); stage(1);

  for (int tt = 0; tt < nt; ++tt) {
    const int b = tt & 3;
    if (tt + 1 < nt) waitvm<4>(); else waitvm<0>();
    bar();  // the only barrier per tile

    const char* Ab = lds + b * 32768 + aoff;
    const char* Bb = lds + b * 32768 + boff;

    // half-phase 1: B frags + A frags 0..3, restage, 16 MFMAs
    i32x8 bf[4], af[4];
    #pragma unroll
    for (int n = 0; n < 4; ++n)
      bf[n] = rd8(Bb + n * 1024);
    #pragma unroll
    for (int m = 0; m < 4; ++m)
      af[m] = rd8(Ab + m * 1024);

    if (tt + 2 < nt) stage(tt + 2);

    #pragma unroll
    for (int m = 0; m < 4; ++m)
      #pragma unroll
      for (int n = 0; n < 4; ++n)
        acc[m][n] = __builtin_amdgcn_mfma_scale_f32_16x16x128_f8f6f4(
            af[m], bf[n], acc[m][n], 4, 4, 0, SC, 0, SC);

    // half-phase 2: A frags 4..7, 16 MFMAs
    i32x8 ag[4];
    #pragma unroll
    for (int m = 0; m < 4; ++m)
      ag[m] = rd8(Ab + (m + 4) * 1024);

    #pragma unroll
    for (int m = 0; m < 4; ++m)
      #pragma unroll
      for (int n = 0; n < 4; ++n)
        acc[m + 4][n] = __builtin_amdgcn_mfma_scale_f32_16x16x128_f8f6f4(
            ag[m], bf[n], acc[m + 4][n], 4, 4, 0, SC, 0, SC);
  }

  // --- epilogue: 16x16 C/D layout col = lane&15, row = (lane>>4)*4 + r ---
  const size_t cRow0 = rowA0 + (size_t)wm * 128;
  const size_t cCol0 = rowB0 + (size_t)wn * 64;
  const int orow = kg * 4;
  #pragma unroll
  for (int m = 0; m < 8; ++m)
    #pragma unroll
    for (int n = 0; n < 4; ++n)
      #pragma unroll
      for (int r = 0; r < 4; ++r)
        C[(cRow0 + m * 16 + orow + r) * N + cCol0 + n * 16 + lrow] =
            acc[m][n][r];
}

// ---------------------------------------------------------------------------
extern "C" void kernel_launch(void* const* d_in, const int* in_sizes, int n_in,
                              void* d_out, int out_size, void* d_ws, size_t ws_size,
                              hipStream_t stream) {
  const float* x = (const float*)d_in[0];
  const float* w = (const float*)d_in[1];
  float* out = (float*)d_out;

  const int K = 4096;
  const int M = in_sizes[0] / K;   // 8192
  const int N = in_sizes[1] / K;   // 4096

  unsigned char* xb = (unsigned char*)d_ws;
  unsigned char* wb = xb + (size_t)M * (K / 2);

  // 32 floats per thread, single pass: gx + gw threads total
  int gx = (M * K) / 32;           // 1048576  (4096 blocks of 256)
  int gw = (N * K) / 32;           // 524288   (2048 blocks of 256)
  int nblk = (gx + gw) / 256;      // 6144
  binarize_fp4_v2<<<dim3(nblk), dim3(256), 0, stream>>>(
      x, w, (uint4*)xb, (uint4*)wb, gx);

  int nbm = M / 256;  // 32
  int nbn = N / 256;  // 16
  gemm_bt_fp4<<<dim3(nbm * nbn), dim3(512), 0, stream>>>(
      xb, wb, out, M, N, K, nbn);
}

// Round 14
// 119.687 us; speedup vs baseline: 1.9125x; 1.0153x over previous
//
#include <hip/hip_runtime.h>
#include <hip/hip_bf16.h>
#include <stdint.h>

typedef int i32x4 __attribute__((ext_vector_type(4)));
typedef int i32x8 __attribute__((ext_vector_type(8)));
typedef float f32x4 __attribute__((ext_vector_type(4)));

// ---------------------------------------------------------------------------
// Pass 1: binarize f32 -> fp4 e2m1 sign nibble (+1=0x2, -1=0xA, 0=0x0),
// packed 2 elems/byte, low nibble = lower k index.
// Round 14: LANE-CONTIGUOUS loads. v2 gave each thread 128 contiguous bytes,
// so one wave-load touched 64 cache lines at 128 B stride (4x request
// amplification at the TA -> ~3 TB/s cap). Now instruction k loads
// base + k*256 + lane: 16 B/lane contiguous = 1 KB/wave-instr, 4 independent
// loads/thread for MLP. Each float4 packs to one ushort stored at 2 B/lane
// (128 B/wave contiguous; write volume only 25 MB).
// ---------------------------------------------------------------------------
__device__ __forceinline__ unsigned int sign_nib(float x) {
  return x > 0.0f ? 0x2u : (x < 0.0f ? 0xAu : 0x0u);
}

__device__ __forceinline__ unsigned short pack4(const float4& a) {
  return (unsigned short)(sign_nib(a.x)
                        | (sign_nib(a.y) << 4)
                        | (sign_nib(a.z) << 8)
                        | (sign_nib(a.w) << 12));
}

__global__ __launch_bounds__(256)
void binarize_fp4_v3(const float* __restrict__ x,
                     const float* __restrict__ w,
                     unsigned short* __restrict__ xb,
                     unsigned short* __restrict__ wb,
                     int bx) {   // bx = number of blocks covering x
  const float4* src;
  unsigned short* dst;
  int b = blockIdx.x;
  if (b < bx) { src = (const float4*)x; dst = xb; }
  else        { src = (const float4*)w; dst = wb; b -= bx; }

  const size_t base = (size_t)b * 1024 + threadIdx.x;
  // 4 independent, perfectly coalesced loads (1 KB per wave-instruction)
  float4 v0 = src[base];
  float4 v1 = src[base + 256];
  float4 v2 = src[base + 512];
  float4 v3 = src[base + 768];

  dst[base]       = pack4(v0);
  dst[base + 256] = pack4(v1);
  dst[base + 512] = pack4(v2);
  dst[base + 768] = pack4(v3);
}

// ---------------------------------------------------------------------------
// Pass 2: C = A * B^T, fp4 +-1/0 inputs, MX-scaled MFMA (scale=1.0), f32 out.
// EXACT: products are +-1/0, f32 accumulation of <=4096 integers is exact.
// UNCHANGED since round 12 (steady-state ~43 us ~= 93% of the fp4 16x16
// MFMA ubench ceiling 7228 TF; conflicts 0 -- at its structural roofline).
// 256x256 tile, BK=128 fp4 (64 B/row), 8 waves (2Mx4N), 4-buffer LDS
// rotation, counted vmcnt, ONE asm barrier per tile, stage(tt+2) after
// the barrier. nt = 32.
// ---------------------------------------------------------------------------
__device__ __forceinline__ void load_lds16(const void* g, void* l) {
  __builtin_amdgcn_global_load_lds(
      (const __attribute__((address_space(1))) void*)g,
      (__attribute__((address_space(3))) void*)l,
      16, 0, 0);
}

__device__ __forceinline__ void bar() {
  asm volatile("s_barrier" ::: "memory");
}
template <int N>
__device__ __forceinline__ void waitvm() {
  asm volatile("s_waitcnt vmcnt(%0)" ::"i"(N) : "memory");
}

__device__ __forceinline__ i32x8 rd8(const char* p) {
  i32x4 q = *(const i32x4*)p;
  return __builtin_shufflevector(q, q, 0, 1, 2, 3, -1, -1, -1, -1);
}

__global__ __launch_bounds__(512, 2)
void gemm_bt_fp4(const unsigned char* __restrict__ A,
                 const unsigned char* __restrict__ B,
                 float* __restrict__ C,
                 int M, int N, int K, int nbn) {
  constexpr int BM = 256, BN = 256;
  __shared__ __attribute__((aligned(16))) char lds[4 * 32768];

  // XCD-aware bijective swizzle (grid = 32*16 = 512, multiple of 8)
  int nwg = gridDim.x;
  int bid = blockIdx.x;
  int cpx = nwg >> 3;
  int swz = (bid & 7) * cpx + (bid >> 3);
  int tm = swz / nbn;
  int tn = swz % nbn;

  const int t = threadIdx.x;
  const int lane = t & 63;
  const int wid = t >> 6;       // 0..7
  const int wm = wid >> 2;      // 0..1  (wave row: 128 rows)
  const int wn = wid & 3;       // 0..3  (wave col: 64 cols)
  const int lrow = lane & 15;
  const int kg = lane >> 4;     // 0..3 (32 contiguous fp4 k-elems = 16 B)

  const int Kb = K >> 1;        // row stride in bytes (fp4 packed)
  const size_t rowA0 = (size_t)tm * BM;
  const size_t rowB0 = (size_t)tn * BN;

  f32x4 acc[8][4] = {};

  const int nt = K / 128;  // 32

  // --- staging lane constants (inverse-swizzled global source) ---
  const int soff0 = wid * 1024 + lane * 16;
  const int srow0 = soff0 >> 6;
  const int scb0 = ((soff0 >> 4) & 3) ^ ((srow0 >> 1) & 3);
  const int soff1 = 8192 + wid * 1024 + lane * 16;
  const int srow1 = soff1 >> 6;
  const int scb1 = ((soff1 >> 4) & 3) ^ ((srow1 >> 1) & 3);

  auto stage = [&](int tt) {
    const int b = tt & 3;
    const int k0b = tt * 64;    // tile K-offset in BYTES (128 fp4 = 64 B)
    load_lds16(A + (rowA0 + srow0) * Kb + k0b + scb0 * 16,
               lds + b * 32768 + wid * 1024);
    load_lds16(A + (rowA0 + srow1) * Kb + k0b + scb1 * 16,
               lds + b * 32768 + 8192 + wid * 1024);
    load_lds16(B + (rowB0 + srow0) * Kb + k0b + scb0 * 16,
               lds + b * 32768 + 16384 + wid * 1024);
    load_lds16(B + (rowB0 + srow1) * Kb + k0b + scb1 * 16,
               lds + b * 32768 + 16384 + 8192 + wid * 1024);
  };

  // --- swizzled read column (byte) within a 64B LDS row (proven 0-conflict)
  const int rcol = ((kg ^ ((lrow >> 1) & 3)) << 4);
  const int aoff = (wm * 128 + lrow) * 64 + rcol;
  const int boff = 16384 + (wn * 64 + lrow) * 64 + rcol;

  const int SC = 0x7F7F7F7F;  // E8M0 scale bytes: 127 -> 2^0

  // prologue: stage tiles 0 and 1 (8 loads outstanding per thread)
  stage(0); stage(1);

  for (int tt = 0; tt < nt; ++tt) {
    const int b = tt & 3;
    if (tt + 1 < nt) waitvm<4>(); else waitvm<0>();
    bar();  // the only barrier per tile

    const char* Ab = lds + b * 32768 + aoff;
    const char* Bb = lds + b * 32768 + boff;

    // half-phase 1: B frags + A frags 0..3, restage, 16 MFMAs
    i32x8 bf[4], af[4];
    #pragma unroll
    for (int n = 0; n < 4; ++n)
      bf[n] = rd8(Bb + n * 1024);
    #pragma unroll
    for (int m = 0; m < 4; ++m)
      af[m] = rd8(Ab + m * 1024);

    if (tt + 2 < nt) stage(tt + 2);

    #pragma unroll
    for (int m = 0; m < 4; ++m)
      #pragma unroll
      for (int n = 0; n < 4; ++n)
        acc[m][n] = __builtin_amdgcn_mfma_scale_f32_16x16x128_f8f6f4(
            af[m], bf[n], acc[m][n], 4, 4, 0, SC, 0, SC);

    // half-phase 2: A frags 4..7, 16 MFMAs
    i32x8 ag[4];
    #pragma unroll
    for (int m = 0; m < 4; ++m)
      ag[m] = rd8(Ab + (m + 4) * 1024);

    #pragma unroll
    for (int m = 0; m < 4; ++m)
      #pragma unroll
      for (int n = 0; n < 4; ++n)
        acc[m + 4][n] = __builtin_amdgcn_mfma_scale_f32_16x16x128_f8f6f4(
            ag[m], bf[n], acc[m + 4][n], 4, 4, 0, SC, 0, SC);
  }

  // --- epilogue: 16x16 C/D layout col = lane&15, row = (lane>>4)*4 + r ---
  const size_t cRow0 = rowA0 + (size_t)wm * 128;
  const size_t cCol0 = rowB0 + (size_t)wn * 64;
  const int orow = kg * 4;
  #pragma unroll
  for (int m = 0; m < 8; ++m)
    #pragma unroll
    for (int n = 0; n < 4; ++n)
      #pragma unroll
      for (int r = 0; r < 4; ++r)
        C[(cRow0 + m * 16 + orow + r) * N + cCol0 + n * 16 + lrow] =
            acc[m][n][r];
}

// ---------------------------------------------------------------------------
extern "C" void kernel_launch(void* const* d_in, const int* in_sizes, int n_in,
                              void* d_out, int out_size, void* d_ws, size_t ws_size,
                              hipStream_t stream) {
  const float* x = (const float*)d_in[0];
  const float* w = (const float*)d_in[1];
  float* out = (float*)d_out;

  const int K = 4096;
  const int M = in_sizes[0] / K;   // 8192
  const int N = in_sizes[1] / K;   // 4096

  unsigned char* xb = (unsigned char*)d_ws;
  unsigned char* wb = xb + (size_t)M * (K / 2);

  // each block: 1024 float4-groups x 4 instr-steps = 4096 floats
  int bxx = (M * K) / 4096;        // 8192 blocks for x
  int bxw = (N * K) / 4096;        // 4096 blocks for w
  binarize_fp4_v3<<<dim3(bxx + bxw), dim3(256), 0, stream>>>(
      x, w, (unsigned short*)xb, (unsigned short*)wb, bxx);

  int nbm = M / 256;  // 32
  int nbn = N / 256;  // 16
  gemm_bt_fp4<<<dim3(nbm * nbn), dim3(512), 0, stream>>>(
      xb, wb, out, M, N, K, nbn);
}